// Round 5
// baseline (668.172 us; speedup 1.0000x reference)
//
#include <hip/hip_runtime.h>
#include <cstdint>

#define N_NODES 100000
#define N_EDGES_C 250000
#define LATENT 128
#define N_FEAT 16
#define OUT_DIM 128
#define D_IN 272      // 16 + 128 + 128
#define KC1 9         // layer-1 K chunks of 32 (K padded 272 -> 288)
#define KC2 8
#define NT1 16        // 256 cols / 16
#define NT2 16
#define NT3 8         // 128 cols / 16
#define EPB 128       // edges per block
#define MT 8          // row-tiles per block (EPB/16)

// swizzled weight sizes in u16 elements
#define SZ1 (KC1*NT1*512)     // 73728
#define SZ2 (KC2*NT2*512)     // 65536
#define SZ3 (KC2*NT3*512)     // 32768
#define SZ_MLP (SZ1+SZ2+SZ3)  // 172032
#define SZ_ALL (2*SZ_MLP)     // 344064

typedef _Float16 f16;
typedef _Float16 f16x8 __attribute__((ext_vector_type(8)));
typedef float f32x4 __attribute__((ext_vector_type(4)));
typedef unsigned short u16;
typedef u16 u16x8 __attribute__((ext_vector_type(8)));

static __device__ __forceinline__ u16 f16_bits(float v) {
    f16 h = (f16)v;
    return __builtin_bit_cast(u16, h);
}

// ---------------------------------------------------------------------------
// Weight swizzle prep (f16): layout = [c][t][quad][n''][j] so a wave's
// B-fragment load is lane*16B contiguous (global_load_dwordx4).
// ---------------------------------------------------------------------------
__global__ void prep_weights(const float* __restrict__ W1a, const float* __restrict__ W2a,
                             const float* __restrict__ W3a, const float* __restrict__ W1b,
                             const float* __restrict__ W2b, const float* __restrict__ W3b,
                             u16* __restrict__ Whi) {
    int idx = blockIdx.x * 256 + threadIdx.x;      // grid is exactly SZ_ALL/256
    int mlp = idx / SZ_MLP;
    int r = idx - mlp * SZ_MLP;
    const float* Wsrc; int NT, Kreal, N, rl;
    if (r < SZ1)            { Wsrc = mlp ? W1b : W1a; NT = NT1; Kreal = D_IN; N = 256; rl = r; }
    else if (r < SZ1 + SZ2) { Wsrc = mlp ? W2b : W2a; NT = NT2; Kreal = 256;  N = 256; rl = r - SZ1; }
    else                    { Wsrc = mlp ? W3b : W3a; NT = NT3; Kreal = 256;  N = 128; rl = r - SZ1 - SZ2; }
    int block  = rl >> 9;
    int within = rl & 511;
    int quad = within >> 7;
    int nn   = (within >> 3) & 15;
    int j    = within & 7;
    int c = block / NT;
    int t = block - c * NT;
    int k = c * 32 + quad * 8 + j;
    int n = t * 16 + nn;
    float w = (k < Kreal) ? Wsrc[(size_t)k * N + n] : 0.f;
    Whi[idx] = f16_bits(w);
}

// ---------------------------------------------------------------------------
// Gather X = concat(ef[16], coords[p1][128], coords[p2][128]) for 128 edges,
// f16, into A-fragment-linear LDS (stride KC1). Non-temporal loads: the
// random gather stream must not evict the L2-resident weight set.
// All 1024 threads; 8 threads per edge, 36 floats each.
// ---------------------------------------------------------------------------
static __device__ __forceinline__ void gatherX(u16* __restrict__ A,
                                               const float* __restrict__ coords,
                                               const float* __restrict__ efeat,
                                               const int* __restrict__ pA,
                                               const int* __restrict__ pB,
                                               int ebase, int tid) {
    int m = tid >> 3;           // edge slot 0..127
    int p = tid & 7;
    int e = ebase + m;
    bool v = e < N_EDGES_C;
    int i1 = pA[m];
    int i2 = pB[m];
    const float* ef = efeat + (size_t)e * N_FEAT;
    const float* c1 = coords + (size_t)i1 * LATENT;
    const float* c2 = coords + (size_t)i2 * LATENT;
    int mt = m >> 4, mr = m & 15;
    int k0 = p * 36;
    #pragma unroll
    for (int kk = 0; kk < 36; kk += 4) {
        int k = k0 + kk;
        f32x4 val;
        if (!v || k >= D_IN)  val = (f32x4){0.f, 0.f, 0.f, 0.f};
        else if (k < 16)      val = __builtin_nontemporal_load((const f32x4*)(ef + k));
        else if (k < 144)     val = __builtin_nontemporal_load((const f32x4*)(c1 + (k - 16)));
        else                  val = __builtin_nontemporal_load((const f32x4*)(c2 + (k - 144)));
        int chunk = k >> 5, quad = (k >> 3) & 3, j = k & 7;
        ushort4 h;
        h.x = f16_bits(val.x); h.y = f16_bits(val.y);
        h.z = f16_bits(val.z); h.w = f16_bits(val.w);
        *(ushort4*)&A[(mt * KC1 + chunk) * 512 + quad * 128 + mr * 8 + j] = h;
    }
}

// ---------------------------------------------------------------------------
// Single-MLP K-loop, MT=8: each B fragment feeds 8 MFMAs (2x arith intensity
// vs EPB=64). 1-deep B prefetch; A loaded per-mt inside the chunk (compiler
// schedules the ds_reads; keeps A liveness flexible under the 128-VGPR cap).
// Compile-time indices only -> registers, no scratch.
// ---------------------------------------------------------------------------
template<int KCL, int KCA, int CT, int NTT>
static __device__ __forceinline__ void kloop(const u16* __restrict__ A,
                                             const u16* __restrict__ W,
                                             int w8, int lane,
                                             f32x4 (&acc)[MT][CT]) {
    const int la8 = lane * 8;
    const int tg0 = w8 * CT;
    u16x8 b[CT];
    #pragma unroll
    for (int t = 0; t < CT; ++t)
        b[t] = *(const u16x8*)&W[(tg0 + t) * 512 + la8];
    #pragma unroll
    for (int c = 0; c < KCL; ++c) {
        u16x8 bn[CT];
        if (c + 1 < KCL) {
            #pragma unroll
            for (int t = 0; t < CT; ++t)
                bn[t] = *(const u16x8*)&W[((c + 1) * NTT + tg0 + t) * 512 + la8];
        }
        #pragma unroll
        for (int mt = 0; mt < MT; ++mt) {
            f16x8 a = __builtin_bit_cast(f16x8, *(const u16x8*)&A[(mt * KCA + c) * 512 + la8]);
            #pragma unroll
            for (int t = 0; t < CT; ++t) {
                f16x8 bf = __builtin_bit_cast(f16x8, b[t]);
                acc[mt][t] = __builtin_amdgcn_mfma_f32_16x16x32_f16(a, bf, acc[mt][t], 0, 0, 0);
            }
        }
        if (c + 1 < KCL) {
            #pragma unroll
            for (int t = 0; t < CT; ++t) b[t] = bn[t];
        }
    }
}

template<int KCL, int KCA, int CT, int NTT>
static __device__ __forceinline__ void layer_mm(const u16* __restrict__ A,
                                                const u16* __restrict__ W,
                                                int w8, int lane,
                                                f32x4 (&acc)[MT][CT]) {
    #pragma unroll
    for (int mt = 0; mt < MT; ++mt)
        #pragma unroll
        for (int t = 0; t < CT; ++t)
            acc[mt][t] = (f32x4){0.f, 0.f, 0.f, 0.f};
    kloop<KCL, KCA, CT, NTT>(A, W, w8, lane, acc);
}

// bias + relu + f16 -> write H into LDS in A-fragment layout (k = n, KC2 stride).
template<int CT>
static __device__ __forceinline__ void epi_relu(u16* __restrict__ H,
                                                const float* __restrict__ bias,
                                                int w8, int lane,
                                                f32x4 (&acc)[MT][CT]) {
    int quad = lane >> 4, ln = lane & 15;
    #pragma unroll
    for (int t = 0; t < CT; ++t) {
        int n = (w8 * CT + t) * 16 + ln;
        float b = bias[n];
        int chunk = n >> 5, q2 = (n >> 3) & 3, j = n & 7;
        #pragma unroll
        for (int mt = 0; mt < MT; ++mt)
            #pragma unroll
            for (int r = 0; r < 4; ++r) {
                float v = acc[mt][t][r] + b;
                v = fmaxf(v, 0.f);
                H[(mt * KC2 + chunk) * 512 + q2 * 128 + (quad * 4 + r) * 8 + j] = f16_bits(v);
            }
    }
}

// 1024 threads (16 waves), 1 block/CU (LDS 140.8 KB), 16 waves/CU — same
// wave count as round 4 (TLP held constant; r3/r4 showed the binding term
// is weight-stream traffic, which this halves again: 2.69 -> 1.34 GB).
// Waves 0-7 run MLP-a, waves 8-15 run MLP-b. Hb overlays X after layer 1.
__global__ void __launch_bounds__(1024, 4)
fused_mlp(const float* __restrict__ coords, const float* __restrict__ efeat,
          const float* __restrict__ nfict,
          const int* __restrict__ port1, const int* __restrict__ port2,
          const float* __restrict__ b1a, const float* __restrict__ b2a, const float* __restrict__ b3a,
          const float* __restrict__ b1b, const float* __restrict__ b2b, const float* __restrict__ b3b,
          const u16* __restrict__ Whi,
          float* __restrict__ out) {
    __shared__ u16 X[MT * KC1 * 512];    // 73728 B: gathered input; becomes Hb
    __shared__ u16 Ha[MT * KC2 * 512];   // 65536 B: MLP-a hidden (H1 then H2)
    __shared__ int pA[EPB], pB[EPB];
    __shared__ float mk[EPB];

    const int tid = threadIdx.x;
    const int lane = tid & 63;
    const int wave = tid >> 6;           // 0..15
    const int ebase = blockIdx.x * EPB;

    if (tid < EPB) {
        int e = ebase + tid;
        bool v = e < N_EDGES_C;
        pA[tid] = v ? port1[e] : 0;
        pB[tid] = v ? port2[e] : 0;
        mk[tid] = v ? nfict[e] : 0.f;
    }
    __syncthreads();
    gatherX(X, coords, efeat, pA, pB, ebase, tid);
    __syncthreads();

    const int msel = wave >> 3;          // 0: MLP-a, 1: MLP-b
    const int w8 = wave & 7;
    const u16* wh = Whi + msel * SZ_MLP;
    const float* B1 = msel ? b1b : b1a;
    const float* B2 = msel ? b2b : b2a;
    const float* B3 = msel ? b3b : b3a;
    const int*   pp = msel ? pB  : pA;
    u16* myH = msel ? X : Ha;            // MLP-b's hidden overlays X

    // ---- layer 1 (272->256): 8 waves x 2 tiles per MLP ----
    f32x4 acc[MT][2];
    layer_mm<KC1, KC1, 2, NT1>(X, wh, w8, lane, acc);
    __syncthreads();                     // ALL waves done reading X
    epi_relu<2>(myH, B1, w8, lane, acc); // b-waves overwrite X-space
    __syncthreads();                     // H1 ready

    // ---- layer 2 (256->256) ----
    layer_mm<KC2, KC2, 2, NT2>(myH, wh + SZ1, w8, lane, acc);
    __syncthreads();                     // H1 reads done
    epi_relu<2>(myH, B2, w8, lane, acc); // H2 over H1
    __syncthreads();                     // H2 ready

    // ---- layer 3 (256->128): 8 waves x 1 tile per MLP ----
    f32x4 acc3[MT][1];
    layer_mm<KC2, KC2, 1, NT3>(myH, wh + SZ1 + SZ2, w8, lane, acc3);

    // ---- scatter: ALL atomics at kernel end, nothing waits on them ----
    int quad = lane >> 4, ln = lane & 15;
    {
        int n = w8 * 16 + ln;
        float bz = B3[n];
        #pragma unroll
        for (int mt = 0; mt < MT; ++mt)
            #pragma unroll
            for (int r = 0; r < 4; ++r) {
                int m = mt * 16 + quad * 4 + r;
                float v = (acc3[mt][0][r] + bz) * mk[m];
                unsafeAtomicAdd(out + (size_t)pp[m] * OUT_DIM + n, v);
            }
    }
}

__global__ void tanh_kernel(float* __restrict__ out, int n) {
    int i = (blockIdx.x * 256 + threadIdx.x) * 4;
    if (i + 3 < n) {
        float4 v = *(float4*)(out + i);
        v.x = tanhf(v.x); v.y = tanhf(v.y); v.z = tanhf(v.z); v.w = tanhf(v.w);
        *(float4*)(out + i) = v;
    } else {
        for (int k = i; k < n; ++k) out[k] = tanhf(out[k]);
    }
}

extern "C" void kernel_launch(void* const* d_in, const int* in_sizes, int n_in,
                              void* d_out, int out_size, void* d_ws, size_t ws_size,
                              hipStream_t stream) {
    const float* coords = (const float*)d_in[0];
    const float* efeat  = (const float*)d_in[1];
    const float* nfict  = (const float*)d_in[2];
    const int*   p1     = (const int*)d_in[3];
    const int*   p2     = (const int*)d_in[4];
    const float* W1a = (const float*)d_in[5];  const float* b1a = (const float*)d_in[6];
    const float* W2a = (const float*)d_in[7];  const float* b2a = (const float*)d_in[8];
    const float* W3a = (const float*)d_in[9];  const float* b3a = (const float*)d_in[10];
    const float* W1b = (const float*)d_in[11]; const float* b1b = (const float*)d_in[12];
    const float* W2b = (const float*)d_in[13]; const float* b2b = (const float*)d_in[14];
    const float* W3b = (const float*)d_in[15]; const float* b3b = (const float*)d_in[16];
    float* out = (float*)d_out;
    u16* Whi = (u16*)d_ws;                 // needs SZ_ALL*2 = 688,128 B of ws

    hipMemsetAsync(d_out, 0, (size_t)out_size * sizeof(float), stream);
    prep_weights<<<SZ_ALL / 256, 256, 0, stream>>>(W1a, W2a, W3a, W1b, W2b, W3b, Whi);
    int nblk = (N_EDGES_C + EPB - 1) / EPB;
    fused_mlp<<<nblk, 1024, 0, stream>>>(coords, efeat, nfict, p1, p2,
                                         b1a, b2a, b3a, b1b, b2b, b3b, Whi, out);
    int n4 = (out_size + 3) / 4;
    tanh_kernel<<<(n4 + 255) / 256, 256, 0, stream>>>(out, out_size);
}

// Round 6
// 499.357 us; speedup vs baseline: 1.3381x; 1.3381x over previous
//
#include <hip/hip_runtime.h>
#include <cstdint>

#define N_NODES 100000
#define N_EDGES_C 250000
#define LATENT 128
#define N_FEAT 16
#define OUT_DIM 128
#define D_IN 272      // 16 + 128 + 128
#define KC1 9         // layer-1 K chunks of 32 (K padded 272 -> 288)
#define KC2 8
#define NT1 16        // 256 cols / 16
#define NT2 16
#define NT3 8         // 128 cols / 16
#define EPB 64        // edges per block  (round-4 geometry: best measured)
#define MT 4          // row-tiles per block (EPB/16)

// swizzled weight sizes in u16 elements
#define SZ1 (KC1*NT1*512)     // 73728
#define SZ2 (KC2*NT2*512)     // 65536
#define SZ3 (KC2*NT3*512)     // 32768
#define SZ_MLP (SZ1+SZ2+SZ3)  // 172032
#define SZ_ALL (2*SZ_MLP)     // 344064
#define WBLK (SZ_ALL/256)     // 1344 weight-swizzle blocks

// f16 input conversion (pre-converted once; bit-identical to converting in
// the gather, since f32->f16 rounding is the same either way)
#define NC4 (N_NODES*LATENT/4)     // 3,200,000 f32x4 groups in coords
#define NE4 (N_EDGES_C*N_FEAT/4)   // 1,000,000 f32x4 groups in efeat
#define CBLK ((NC4+NE4+255)/256)   // conversion blocks

typedef _Float16 f16;
typedef _Float16 f16x8 __attribute__((ext_vector_type(8)));
typedef float f32x4 __attribute__((ext_vector_type(4)));
typedef unsigned short u16;
typedef u16 u16x8 __attribute__((ext_vector_type(8)));

// static device arrays: no dependence on workspace size
__device__ u16 g_coords_h[(size_t)N_NODES * LATENT];   // 25.6 MB
__device__ u16 g_efeat_h[(size_t)N_EDGES_C * N_FEAT];  // 8 MB

static __device__ __forceinline__ u16 f16_bits(float v) {
    f16 h = (f16)v;
    return __builtin_bit_cast(u16, h);
}

// ---------------------------------------------------------------------------
// prep_all: blocks [0,WBLK) swizzle weights into Whi (f16, MFMA-B-fragment
// linear layout); blocks [WBLK, WBLK+CBLK) convert coords/efeat f32->f16.
// ---------------------------------------------------------------------------
__global__ void prep_all(const float* __restrict__ W1a, const float* __restrict__ W2a,
                         const float* __restrict__ W3a, const float* __restrict__ W1b,
                         const float* __restrict__ W2b, const float* __restrict__ W3b,
                         const float* __restrict__ coords, const float* __restrict__ efeat,
                         u16* __restrict__ Whi) {
    if (blockIdx.x < WBLK) {
        int idx = blockIdx.x * 256 + threadIdx.x;
        int mlp = idx / SZ_MLP;
        int r = idx - mlp * SZ_MLP;
        const float* Wsrc; int NT, Kreal, N, rl;
        if (r < SZ1)            { Wsrc = mlp ? W1b : W1a; NT = NT1; Kreal = D_IN; N = 256; rl = r; }
        else if (r < SZ1 + SZ2) { Wsrc = mlp ? W2b : W2a; NT = NT2; Kreal = 256;  N = 256; rl = r - SZ1; }
        else                    { Wsrc = mlp ? W3b : W3a; NT = NT3; Kreal = 256;  N = 128; rl = r - SZ1 - SZ2; }
        int block  = rl >> 9;
        int within = rl & 511;
        int quad = within >> 7;
        int nn   = (within >> 3) & 15;
        int j    = within & 7;
        int c = block / NT;
        int t = block - c * NT;
        int k = c * 32 + quad * 8 + j;
        int n = t * 16 + nn;
        float w = (k < Kreal) ? Wsrc[(size_t)k * N + n] : 0.f;
        Whi[idx] = f16_bits(w);
    } else {
        int i = (blockIdx.x - WBLK) * 256 + threadIdx.x;   // f32x4 group index
        const float* src;
        u16* dst;
        if (i < NC4)               { src = coords + (size_t)i * 4; dst = g_coords_h + (size_t)i * 4; }
        else if (i < NC4 + NE4)    { int j = i - NC4; src = efeat + (size_t)j * 4; dst = g_efeat_h + (size_t)j * 4; }
        else return;
        f32x4 v = *(const f32x4*)src;
        ushort4 h;
        h.x = f16_bits(v.x); h.y = f16_bits(v.y);
        h.z = f16_bits(v.z); h.w = f16_bits(v.w);
        *(ushort4*)dst = h;
    }
}

// ---------------------------------------------------------------------------
// Gather X = concat(ef[16], coords[p1][128], coords[p2][128]) for 64 edges,
// already-f16 sources, into A-fragment-linear LDS (stride KC1). Half the
// bytes of the f32 gather and no per-element cvt. 8 threads per edge; each
// handles 8-f16-aligned chunks ci = p, p+8, ... (< 36). Non-temporal loads:
// the random gather stream must not evict the L2-resident weight set.
// ---------------------------------------------------------------------------
static __device__ __forceinline__ void gatherX(u16* __restrict__ A,
                                               const int* __restrict__ pA,
                                               const int* __restrict__ pB,
                                               int ebase, int tid) {
    int m = tid >> 3;           // edge slot 0..63
    int p = tid & 7;
    int e = ebase + m;
    bool v = e < N_EDGES_C;
    int i1 = pA[m];
    int i2 = pB[m];
    const u16* ef = g_efeat_h + (size_t)e * N_FEAT;
    const u16* c1 = g_coords_h + (size_t)i1 * LATENT;
    const u16* c2 = g_coords_h + (size_t)i2 * LATENT;
    int mt = m >> 4, mr = m & 15;
    #pragma unroll
    for (int it = 0; it < 5; ++it) {
        int ci = p + it * 8;                 // 8-f16 chunk index, 36 chunks total
        if (ci >= 36) break;
        int k = ci * 8;
        u16x8 h;
        if (!v || k >= D_IN)  h = (u16x8){0, 0, 0, 0, 0, 0, 0, 0};
        else if (k < 16)      h = __builtin_nontemporal_load((const u16x8*)(ef + k));
        else if (k < 144)     h = __builtin_nontemporal_load((const u16x8*)(c1 + (k - 16)));
        else                  h = __builtin_nontemporal_load((const u16x8*)(c2 + (k - 144)));
        int chunk = k >> 5, quad = (k >> 3) & 3;
        *(u16x8*)&A[(mt * KC1 + chunk) * 512 + quad * 128 + mr * 8] = h;
    }
}

// ---------------------------------------------------------------------------
// Single-MLP K-loop, MT=4: each B fragment feeds 4 MFMAs. 1-deep B prefetch;
// A loaded per-chunk from LDS. Compile-time indices only -> registers.
// ---------------------------------------------------------------------------
template<int KCL, int KCA, int CT, int NTT>
static __device__ __forceinline__ void kloop(const u16* __restrict__ A,
                                             const u16* __restrict__ W,
                                             int w4, int lane,
                                             f32x4 (&acc)[MT][CT]) {
    const int la8 = lane * 8;
    const int tg0 = w4 * CT;
    u16x8 b[CT];
    #pragma unroll
    for (int t = 0; t < CT; ++t)
        b[t] = *(const u16x8*)&W[(tg0 + t) * 512 + la8];
    #pragma unroll
    for (int c = 0; c < KCL; ++c) {
        u16x8 bn[CT];
        if (c + 1 < KCL) {
            #pragma unroll
            for (int t = 0; t < CT; ++t)
                bn[t] = *(const u16x8*)&W[((c + 1) * NTT + tg0 + t) * 512 + la8];
        }
        f16x8 a[MT];
        #pragma unroll
        for (int mt = 0; mt < MT; ++mt)
            a[mt] = __builtin_bit_cast(f16x8, *(const u16x8*)&A[(mt * KCA + c) * 512 + la8]);
        #pragma unroll
        for (int t = 0; t < CT; ++t) {
            f16x8 bf = __builtin_bit_cast(f16x8, b[t]);
            #pragma unroll
            for (int mt = 0; mt < MT; ++mt)
                acc[mt][t] = __builtin_amdgcn_mfma_f32_16x16x32_f16(a[mt], bf, acc[mt][t], 0, 0, 0);
        }
        if (c + 1 < KCL) {
            #pragma unroll
            for (int t = 0; t < CT; ++t) b[t] = bn[t];
        }
    }
}

template<int KCL, int KCA, int CT, int NTT>
static __device__ __forceinline__ void layer_mm(const u16* __restrict__ A,
                                                const u16* __restrict__ W,
                                                int w4, int lane,
                                                f32x4 (&acc)[MT][CT]) {
    #pragma unroll
    for (int mt = 0; mt < MT; ++mt)
        #pragma unroll
        for (int t = 0; t < CT; ++t)
            acc[mt][t] = (f32x4){0.f, 0.f, 0.f, 0.f};
    kloop<KCL, KCA, CT, NTT>(A, W, w4, lane, acc);
}

// bias + relu + f16 -> write H into LDS in A-fragment layout (k = n, KC2 stride).
template<int CT>
static __device__ __forceinline__ void epi_relu(u16* __restrict__ H,
                                                const float* __restrict__ bias,
                                                int w4, int lane,
                                                f32x4 (&acc)[MT][CT]) {
    int quad = lane >> 4, ln = lane & 15;
    #pragma unroll
    for (int t = 0; t < CT; ++t) {
        int n = (w4 * CT + t) * 16 + ln;
        float b = bias[n];
        int chunk = n >> 5, q2 = (n >> 3) & 3, j = n & 7;
        #pragma unroll
        for (int mt = 0; mt < MT; ++mt)
            #pragma unroll
            for (int r = 0; r < 4; ++r) {
                float v = acc[mt][t][r] + b;
                v = fmaxf(v, 0.f);
                H[(mt * KC2 + chunk) * 512 + q2 * 128 + (quad * 4 + r) * 8 + j] = f16_bits(v);
            }
    }
}

// Round-4 geometry (best measured): 512 threads (8 waves), waves 0-3 MLP-a,
// 4-7 MLP-b; LDS 70.6 KB -> 2 blocks/CU, 16 waves/CU. Hb overlays X after L1.
__global__ void __launch_bounds__(512, 4)
fused_mlp(const float* __restrict__ nfict,
          const int* __restrict__ port1, const int* __restrict__ port2,
          const float* __restrict__ b1a, const float* __restrict__ b2a, const float* __restrict__ b3a,
          const float* __restrict__ b1b, const float* __restrict__ b2b, const float* __restrict__ b3b,
          const u16* __restrict__ Whi,
          float* __restrict__ out) {
    __shared__ u16 X[MT * KC1 * 512];    // 36864 B: gathered input; becomes Hb
    __shared__ u16 Ha[MT * KC2 * 512];   // 32768 B: MLP-a hidden (H1 then H2)
    __shared__ int pA[EPB], pB[EPB];
    __shared__ float mk[EPB];

    const int tid = threadIdx.x;
    const int lane = tid & 63;
    const int wave = tid >> 6;           // 0..7
    const int ebase = blockIdx.x * EPB;

    if (tid < EPB) {
        int e = ebase + tid;
        bool v = e < N_EDGES_C;
        pA[tid] = v ? port1[e] : 0;
        pB[tid] = v ? port2[e] : 0;
        mk[tid] = v ? nfict[e] : 0.f;
    }
    __syncthreads();
    gatherX(X, pA, pB, ebase, tid);
    __syncthreads();

    const int msel = wave >> 2;          // 0: MLP-a, 1: MLP-b
    const int w4 = wave & 3;
    const u16* wh = Whi + msel * SZ_MLP;
    const float* B1 = msel ? b1b : b1a;
    const float* B2 = msel ? b2b : b2a;
    const float* B3 = msel ? b3b : b3a;
    const int*   pp = msel ? pB  : pA;
    u16* myH = msel ? X : Ha;            // MLP-b's hidden overlays X

    // ---- layer 1 (272->256): 4 waves x 4 tiles per MLP ----
    f32x4 acc[MT][4];
    layer_mm<KC1, KC1, 4, NT1>(X, wh, w4, lane, acc);
    __syncthreads();                     // ALL waves done reading X
    epi_relu<4>(myH, B1, w4, lane, acc); // b-waves overwrite X-space
    __syncthreads();                     // H1 ready

    // ---- layer 2 (256->256) ----
    layer_mm<KC2, KC2, 4, NT2>(myH, wh + SZ1, w4, lane, acc);
    __syncthreads();                     // H1 reads done
    epi_relu<4>(myH, B2, w4, lane, acc); // H2 over H1
    __syncthreads();                     // H2 ready

    // ---- layer 3 (256->128): 4 waves x 2 tiles per MLP ----
    f32x4 acc3[MT][2];
    layer_mm<KC2, KC2, 2, NT3>(myH, wh + SZ1 + SZ2, w4, lane, acc3);

    // ---- scatter: ALL atomics at kernel end, nothing waits on them ----
    int quad = lane >> 4, ln = lane & 15;
    #pragma unroll
    for (int t = 0; t < 2; ++t) {
        int n = (w4 * 2 + t) * 16 + ln;
        float bz = B3[n];
        #pragma unroll
        for (int mt = 0; mt < MT; ++mt)
            #pragma unroll
            for (int r = 0; r < 4; ++r) {
                int m = mt * 16 + quad * 4 + r;
                float v = (acc3[mt][t][r] + bz) * mk[m];
                unsafeAtomicAdd(out + (size_t)pp[m] * OUT_DIM + n, v);
            }
    }
}

__global__ void tanh_kernel(float* __restrict__ out, int n) {
    int i = (blockIdx.x * 256 + threadIdx.x) * 4;
    if (i + 3 < n) {
        float4 v = *(float4*)(out + i);
        v.x = tanhf(v.x); v.y = tanhf(v.y); v.z = tanhf(v.z); v.w = tanhf(v.w);
        *(float4*)(out + i) = v;
    } else {
        for (int k = i; k < n; ++k) out[k] = tanhf(out[k]);
    }
}

extern "C" void kernel_launch(void* const* d_in, const int* in_sizes, int n_in,
                              void* d_out, int out_size, void* d_ws, size_t ws_size,
                              hipStream_t stream) {
    const float* coords = (const float*)d_in[0];
    const float* efeat  = (const float*)d_in[1];
    const float* nfict  = (const float*)d_in[2];
    const int*   p1     = (const int*)d_in[3];
    const int*   p2     = (const int*)d_in[4];
    const float* W1a = (const float*)d_in[5];  const float* b1a = (const float*)d_in[6];
    const float* W2a = (const float*)d_in[7];  const float* b2a = (const float*)d_in[8];
    const float* W3a = (const float*)d_in[9];  const float* b3a = (const float*)d_in[10];
    const float* W1b = (const float*)d_in[11]; const float* b1b = (const float*)d_in[12];
    const float* W2b = (const float*)d_in[13]; const float* b2b = (const float*)d_in[14];
    const float* W3b = (const float*)d_in[15]; const float* b3b = (const float*)d_in[16];
    float* out = (float*)d_out;
    u16* Whi = (u16*)d_ws;                 // needs SZ_ALL*2 = 688,128 B of ws

    hipMemsetAsync(d_out, 0, (size_t)out_size * sizeof(float), stream);
    prep_all<<<WBLK + CBLK, 256, 0, stream>>>(W1a, W2a, W3a, W1b, W2b, W3b,
                                              coords, efeat, Whi);
    int nblk = (N_EDGES_C + EPB - 1) / EPB;
    fused_mlp<<<nblk, 512, 0, stream>>>(nfict, p1, p2,
                                        b1a, b2a, b3a, b1b, b2b, b3b, Whi, out);
    int n4 = (out_size + 3) / 4;
    tanh_kernel<<<(n4 + 255) / 256, 256, 0, stream>>>(out, out_size);
}